// Round 18
// baseline (1802.572 us; speedup 1.0000x reference)
//
#include <hip/hip_runtime.h>
#include <stdint.h>

// ModeloNeuralVasicek — two-phase mean-recursion.
// Round 18: R17 (best, 1728us total / 615ns-step) + two cuts:
//  (a) phase-1 batching: 16 (b,s) units per wave -> 2520 blocks (was 40320);
//      block preamble amortized 16x. Phase1+launch was ~178us of the total
//      vs ~15-20us of real work.
//  (b) MFMA column chains depth 4 -> 2: two accumulators per column tile
//      (tiles 0-1 and 2-3), summed post-fence. Cuts ~2 dependent MFMA
//      latencies off the serial chain; +4 VALU adds (off-chain cheap).
// absmax may shift off 0.0078125 (K-split sum order); stays f16-noise.

#define NSTEPS 2520
#define NB 64
#define NT 256
#define NQ 256
#define NMAT 7
#define P1UNITS 16

typedef uint32_t u32x4 __attribute__((ext_vector_type(4)));
typedef float f32x4 __attribute__((ext_vector_type(4)));

__device__ __forceinline__ uint32_t rotl32(uint32_t v, int n) {
  return (v << n) | (v >> (32 - n));
}

// Threefry-2x32, 20 rounds — matches jax._src.prng.threefry2x32 exactly.
__device__ __forceinline__ void tf2x32(uint32_t k0, uint32_t k1,
                                       uint32_t x0, uint32_t x1,
                                       uint32_t& o0, uint32_t& o1) {
  const uint32_t k2 = k0 ^ k1 ^ 0x1BD11BDAu;
  x0 += k0; x1 += k1;
#define R4(a,b,c,d) \
  x0 += x1; x1 = rotl32(x1,(a)); x1 ^= x0; \
  x0 += x1; x1 = rotl32(x1,(b)); x1 ^= x0; \
  x0 += x1; x1 = rotl32(x1,(c)); x1 ^= x0; \
  x0 += x1; x1 = rotl32(x1,(d)); x1 ^= x0;
  R4(13,15,26,6)  x0 += k1; x1 += k2 + 1u;
  R4(17,29,16,24) x0 += k2; x1 += k0 + 2u;
  R4(13,15,26,6)  x0 += k0; x1 += k1 + 3u;
  R4(17,29,16,24) x0 += k1; x1 += k2 + 4u;
  R4(13,15,26,6)  x0 += k2; x1 += k0 + 5u;
#undef R4
  o0 = x0; o1 = x1;
}

// fast reciprocal: v_rcp + one Newton step (~1e-7 rel; replaces full f32 div)
__device__ __forceinline__ float fast_rcp(float q) {
  float r = __builtin_amdgcn_rcpf(q);
  r = __builtin_fmaf(r, __builtin_fmaf(-q, r, 1.0f), r);
  return r;
}

// Eigen/XLA generic_fast_tanh_float (preamble only; keep full precision).
__device__ __forceinline__ float eigen_tanh(float a_x) {
  float x = fminf(fmaxf(a_x, -7.90531110763549805f), 7.90531110763549805f);
  float x2 = x * x;
  float p = __builtin_fmaf(x2, -2.76076847742355e-16f, 2.00018790482477e-13f);
  p = __builtin_fmaf(x2, p, -8.60467152213735e-11f);
  p = __builtin_fmaf(x2, p, 5.12229709037114e-08f);
  p = __builtin_fmaf(x2, p, 1.48572235717979e-05f);
  p = __builtin_fmaf(x2, p, 6.37261928875436e-04f);
  p = __builtin_fmaf(x2, p, 4.89352455891786e-03f);
  p = x * p;
  float q = __builtin_fmaf(x2, 1.19825839466702e-06f, 1.18534705686654e-04f);
  q = __builtin_fmaf(x2, q, 2.26843463243900e-03f);
  q = __builtin_fmaf(x2, q, 4.89352518554385e-03f);
  float rr = p / q;
  return (fabsf(a_x) < 0.0004f) ? a_x : rr;
}

// Eigen/XLA erf polynomial with rcp-division (scan loop hot path).
__device__ __forceinline__ float eigen_erf_fast(float a_x) {
  float x = fminf(fmaxf(a_x, -4.0f), 4.0f);
  float x2 = x * x;
  float p = __builtin_fmaf(x2, -2.72614225801306e-10f, 2.77068142495902e-08f);
  p = __builtin_fmaf(x2, p, -2.10102402082508e-06f);
  p = __builtin_fmaf(x2, p, -5.69250639462346e-05f);
  p = __builtin_fmaf(x2, p, -7.34990630326855e-04f);
  p = __builtin_fmaf(x2, p, -2.95459980854025e-03f);
  p = __builtin_fmaf(x2, p, -1.60960333262415e-02f);
  p = x * p;
  float q = __builtin_fmaf(x2, -1.45660718464996e-05f, -2.13374055278905e-04f);
  q = __builtin_fmaf(x2, q, -1.68282697438203e-03f);
  q = __builtin_fmaf(x2, q, -7.37332916720468e-03f);
  q = __builtin_fmaf(x2, q, -1.42647390514189e-02f);
  return p * fast_rcp(q);
}

__device__ __forceinline__ float gelu_fast(float x) {
  float t = x * 0.7071067811865475f;
  float e = eigen_erf_fast(t);
  return x * (e + 1.0f) * 0.5f;
}

// fast softplus: __expf/__logf (v_exp/v_log based), abs err ~1e-6
__device__ __forceinline__ float softplus_fast(float x) {
  float e = __expf(-fabsf(x));
  return fmaxf(x, 0.0f) + __logf(1.0f + e);
}

// XLA chlo.erf_inv f32 (Giles polynomial) — phase 1 only, keep exact.
__device__ __forceinline__ float erfinv_xla(float x) {
  float w = -logf((1.0f - x) * (1.0f + x));
  float p;
  if (w < 5.0f) {
    w = w - 2.5f;
    p = 2.81022636e-08f;
    p = __builtin_fmaf(p, w, 3.43273939e-07f);
    p = __builtin_fmaf(p, w, -3.5233877e-06f);
    p = __builtin_fmaf(p, w, -4.39150654e-06f);
    p = __builtin_fmaf(p, w, 0.00021858087f);
    p = __builtin_fmaf(p, w, -0.00125372503f);
    p = __builtin_fmaf(p, w, -0.00417768164f);
    p = __builtin_fmaf(p, w, 0.246640727f);
    p = __builtin_fmaf(p, w, 1.50140941f);
  } else {
    w = sqrtf(w) - 3.0f;
    p = -0.000200214257f;
    p = __builtin_fmaf(p, w, 0.000100950558f);
    p = __builtin_fmaf(p, w, 0.00134934322f);
    p = __builtin_fmaf(p, w, -0.00367342844f);
    p = __builtin_fmaf(p, w, 0.00573950773f);
    p = __builtin_fmaf(p, w, -0.0076224613f);
    p = __builtin_fmaf(p, w, 0.00943887047f);
    p = __builtin_fmaf(p, w, 1.00167406f);
    p = __builtin_fmaf(p, w, 2.83297682f);
  }
  return p * x;
}

__device__ __forceinline__ float bits_to_normal(uint32_t bits) {
  const float MINVAL = -0.999999940395355224609375f;
  uint32_t fb = (bits >> 9) | 0x3F800000u;
  float f01 = __uint_as_float(fb) - 1.0f;
  float u = f01 * 2.0f + MINVAL;
  u = fmaxf(u, MINVAL);
  return 1.41421356237309515f * erfinv_xla(u);
}

__device__ __forceinline__ uint16_t f32_to_f16bits(float x) {
  _Float16 hv = (_Float16)x;  // RNE
  return __builtin_bit_cast(uint16_t, hv);
}

__device__ __forceinline__ uint32_t pack_f16x2(float lo, float hi) {
  return (uint32_t)f32_to_f16bits(lo) | ((uint32_t)f32_to_f16bits(hi) << 16);
}

// DPP add: v += dpp_move(v) — VALU pipe. Template => constant ctrl/masks.
template <int CTRL, int RMASK>
__device__ __forceinline__ float dpp_add(float v) {
  int x = __builtin_amdgcn_update_dpp(0, __float_as_int(v), CTRL, RMASK, 0xf, true);
  return v + __int_as_float(x);
}

#define DTF  0.00396825396825396826f
#define SQDT 0.06299407883487120442f
#define TSTEP (1.0f / 2519.0f)

// ---------------- Phase 1: mean_dW[b][s] — batched, 2520 blocks ------------
// Each wave handles P1UNITS consecutive (b,s) pairs; units are independent
// so ILP hides the threefry/erfinv/shuffle latency; preamble amortized 16x.
__global__ __launch_bounds__(256)
void vasicek_phase1_meandw(float* __restrict__ ws) {
  const int tid = threadIdx.x;
  const int lane = tid & 63;
  const int wv = tid >> 6;
  const int base = (blockIdx.x * 4 + wv) * P1UNITS;   // 0..161280-16

#pragma unroll 4
  for (int u = 0; u < P1UNITS; ++u) {
    const int wid = base + u;
    const int b = wid / NSTEPS;
    const int s = wid - b * NSTEPS;

    uint32_t kA, kB;
    tf2x32(0u, 1u, 0u, (uint32_t)s, kA, kB);    // split(key(1))[s]

    float sum = 0.f;
#pragma unroll
    for (int i = 0; i < 4; ++i) {
      uint32_t cnt = (uint32_t)(b * NQ + lane + i * 64);
      uint32_t q0, q1;
      tf2x32(kA, kB, 0u, cnt, q0, q1);
      sum += bits_to_normal(q0 ^ q1) * SQDT;
    }
    sum += __shfl_xor(sum, 32, 64); sum += __shfl_xor(sum, 16, 64);
    sum += __shfl_xor(sum, 8, 64);  sum += __shfl_xor(sum, 4, 64);
    sum += __shfl_xor(sum, 2, 64);  sum += __shfl_xor(sum, 1, 64);
    if (lane == 0) ws[b * NSTEPS + s] = sum * (1.0f / 256.0f);
  }
}

// ---- B-fragment machinery, k-PERMUTED to match the packed h1 layout:
// h1p dword l = (h1[l], h1[l+64]) => B dword d of tile T (lane q,n) must hold
// W2 rows (16T+4q+d, 64+16T+4q+d) at column 16*(4*half+C)+n, f16x2 packed.
#define BDECL(T, C) u32x4 b_##T##_##C;
#define BINIT(T, C) { \
  const int col_ = 16 * (4 * half + (C)) + n; \
  const int r0_ = 16 * (T) + 4 * q; \
  b_##T##_##C = (u32x4){ \
    pack_f16x2(W2src[(r0_ + 0) * 128 + col_], W2src[(r0_ + 64) * 128 + col_]), \
    pack_f16x2(W2src[(r0_ + 1) * 128 + col_], W2src[(r0_ + 65) * 128 + col_]), \
    pack_f16x2(W2src[(r0_ + 2) * 128 + col_], W2src[(r0_ + 66) * 128 + col_]), \
    pack_f16x2(W2src[(r0_ + 3) * 128 + col_], W2src[(r0_ + 67) * 128 + col_])}; \
  asm volatile("" : "+a"(b_##T##_##C)); /* pin in AGPR quad */ \
}
#define MFMA1(ACC, AF, BF) \
  asm("v_mfma_f32_16x16x32_f16 %0, %1, %2, %0" : "+v"(ACC) : "v"(AF), "a"(BF));
// depth-2 chains: tiles 0,1 into ACCV; tiles 2,3 into ACCW (summed post-fence)
#define COLCHAIN2(ACCV, ACCW, C) \
  MFMA1(ACCV, af0, b_0_##C) MFMA1(ACCV, af1, b_1_##C) \
  MFMA1(ACCW, af2, b_2_##C) MFMA1(ACCW, af3, b_3_##C)

// ---------------- Phase 2: scan, 64 blocks x 256 ---------------------------
__global__
__attribute__((amdgpu_flat_work_group_size(256, 256)))
__attribute__((amdgpu_waves_per_eu(1, 1)))
void vasicek_phase2_scan(
    const float* __restrict__ X, const float* __restrict__ r_ult,
    const float* __restrict__ mats,
    const float* __restrict__ Wp, const float* __restrict__ bp,
    const float* __restrict__ ln_g, const float* __restrict__ ln_b,
    const float* __restrict__ muW1, const float* __restrict__ mub1,
    const float* __restrict__ muW2, const float* __restrict__ mub2,
    const float* __restrict__ muW3, const float* __restrict__ mub3,
    const float* __restrict__ siW1, const float* __restrict__ sib1,
    const float* __restrict__ siW2, const float* __restrict__ sib2,
    const float* __restrict__ siW3, const float* __restrict__ sib3,
    const float* __restrict__ ws, float* __restrict__ out) {
  __shared__ __align__(16) uint32_t h1p[4][64];   // per-wave packed h1 (k-permuted)
  __shared__ float meanw[NSTEPS];
  __shared__ float part[256];
  __shared__ float mbuf[64];
  __shared__ float ctx_lds[192];
  __shared__ __align__(16) float msum[2][4];      // [parity][wave]

  const int t = threadIdx.x;
  const int b = blockIdx.x;
  const int lane = t & 63;
  const int wv = t >> 6;

  for (int i = t; i < NSTEPS; i += 256) meanw[i] = ws[b * NSTEPS + i];

  // ---- context aggregator (all 256 threads, one T-row each) ----
  float h[64];
  {
    float x0 = X[(b * NT + t) * 2 + 0];
    float x1 = X[(b * NT + t) * 2 + 1];
    float s = 0.f;
#pragma unroll
    for (int c = 0; c < 64; ++c) {
      float pre = __builtin_fmaf(x1, Wp[64 + c], x0 * Wp[c]) + bp[c];
      h[c] = eigen_tanh(pre);
      s += h[c];
    }
    float m = s * 0.015625f;
    float vs = 0.f;
#pragma unroll
    for (int c = 0; c < 64; ++c) { float d = h[c] - m; vs = __builtin_fmaf(d, d, vs); }
    float den = sqrtf(vs * 0.015625f + 1e-5f);
#pragma unroll
    for (int c = 0; c < 64; ++c)
      h[c] = ((h[c] - m) / den) * ln_g[c] + ln_b[c];
  }
#pragma unroll
  for (int c = 0; c < 64; ++c) {
    float v = h[c];
    v += __shfl_xor(v, 32, 64); v += __shfl_xor(v, 16, 64);
    v += __shfl_xor(v, 8, 64);  v += __shfl_xor(v, 4, 64);
    v += __shfl_xor(v, 2, 64);  v += __shfl_xor(v, 1, 64);
    if (lane == 0) part[wv * 64 + c] = v;
  }
  __syncthreads();
  if (t < 64) {
    float m = ((part[t] + part[64 + t]) + (part[128 + t] + part[192 + t])) * (1.0f / 256.0f);
    mbuf[t] = m;
    ctx_lds[t] = m;
  }
  __syncthreads();
#pragma unroll
  for (int c = 0; c < 64; ++c) {
    float d = h[c] - mbuf[c];
    float v = d * d;
    v += __shfl_xor(v, 32, 64); v += __shfl_xor(v, 16, 64);
    v += __shfl_xor(v, 8, 64);  v += __shfl_xor(v, 4, 64);
    v += __shfl_xor(v, 2, 64);  v += __shfl_xor(v, 1, 64);
    if (lane == 0) part[wv * 64 + c] = v;
  }
  if (t == 255) {
#pragma unroll
    for (int c = 0; c < 64; ++c) ctx_lds[128 + c] = h[c];
  }
  __syncthreads();
  if (t < 64) {
    float vs = (part[t] + part[64 + t]) + (part[128 + t] + part[192 + t]);
    ctx_lds[64 + t] = sqrtf(vs / 255.0f);
  }
  __syncthreads();

  // ---- per-wave roles: mlp = wv>>1 (0=mu,1=si), half = wv&1 ----
  const int mlp = wv >> 1;
  const int half = wv & 1;
  const int j0 = lane, j1 = lane + 64;        // layer-1 ownership (full h1)
  const int jE = 64 * half + lane;            // epilogue ownership (h2 half)
  const float* W1 = mlp == 0 ? muW1 : siW1;
  const float* W2src = mlp == 0 ? muW2 : siW2;
  float c1a = (mlp == 0 ? mub1 : sib1)[j0];
  float c1b = (mlp == 0 ? mub1 : sib1)[j1];
  for (int c = 0; c < 192; ++c) {
    const float cx = ctx_lds[c];
    c1a = __builtin_fmaf(cx, W1[(2 + c) * 128 + j0], c1a);
    c1b = __builtin_fmaf(cx, W1[(2 + c) * 128 + j1], c1b);
  }
  const float w10a = W1[j0], w11a = W1[128 + j0];
  const float w10b = W1[j1], w11b = W1[128 + j1];
  const float b2E = (mlp == 0 ? mub2 : sib2)[jE];
  const float w3E = (mlp == 0 ? muW3 : siW3)[jE];
  const float b3mu = mub3[0], b3si = sib3[0];

  const int q = lane >> 4, n = lane & 15;

  // this wave's 4 col-tiles of its W2 -> 16 AGPR quads (one-time; pinned)
  BDECL(0,0) BDECL(0,1) BDECL(0,2) BDECL(0,3)
  BDECL(1,0) BDECL(1,1) BDECL(1,2) BDECL(1,3)
  BDECL(2,0) BDECL(2,1) BDECL(2,2) BDECL(2,3)
  BDECL(3,0) BDECL(3,1) BDECL(3,2) BDECL(3,3)
  BINIT(0,0) BINIT(0,1) BINIT(0,2) BINIT(0,3)
  BINIT(1,0) BINIT(1,1) BINIT(1,2) BINIT(1,3)
  BINIT(2,0) BINIT(2,1) BINIT(2,2) BINIT(2,3)
  BINIT(3,0) BINIT(3,1) BINIT(3,2) BINIT(3,3)

  const u32x4* hq = (const u32x4*)(&h1p[wv][0]);   // 16 chunks of 4 dwords

  float r_mean = r_ult[b];
  float area = 0.f;

#pragma unroll 1
  for (int s = 0; s < NSTEPS; ++s) {
    const float tval = TSTEP * (float)s;
    // layer 1: this wave computes its MLP's FULL h1; ONE packed b32 write
    float ha = gelu_fast(__builtin_fmaf(tval, w11a, __builtin_fmaf(r_mean, w10a, c1a)));
    float hb = gelu_fast(__builtin_fmaf(tval, w11b, __builtin_fmaf(r_mean, w10b, c1b)));
    h1p[wv][lane] = pack_f16x2(ha, hb);      // dword l = (h1[l], h1[l+64])
    // same-wave LDS write->read (in-order at LDS unit; R11/R13-validated)
    u32x4 af0 = hq[q], af1 = hq[4 + q], af2 = hq[8 + q], af3 = hq[12 + q];

    // layer 2: depth-2 MFMA chains (K split 0-1 / 2-3), summed after fence
    f32x4 av0 = {0,0,0,0}, av1 = {0,0,0,0}, av2 = {0,0,0,0}, av3 = {0,0,0,0};
    f32x4 aw0 = {0,0,0,0}, aw1 = {0,0,0,0}, aw2 = {0,0,0,0}, aw3 = {0,0,0,0};
    COLCHAIN2(av0, aw0, 0) COLCHAIN2(av1, aw1, 1)
    COLCHAIN2(av2, aw2, 2) COLCHAIN2(av3, aw3, 3)
    // MFMA dst -> VALU read hazard fence
    asm volatile("s_nop 7\n\ts_nop 7"
                 : "+v"(av0), "+v"(av1), "+v"(av2), "+v"(av3),
                   "+v"(aw0), "+v"(aw1), "+v"(aw2), "+v"(aw3));

    // all D rows identical => acc_c[0] = partial h2[64*half + 16c + n]; c=q
    float h2v = q == 0 ? av0[0] : q == 1 ? av1[0] : q == 2 ? av2[0] : av3[0];
    float h2w = q == 0 ? aw0[0] : q == 1 ? aw1[0] : q == 2 ? aw2[0] : aw3[0];
    float h2E = h2v + h2w;

    // layer 3 partial via DPP reduce (VALU pipe): total lands in lane 63
    float p = gelu_fast(h2E + b2E) * w3E;
    p = dpp_add<0x111, 0xf>(p);   // row_shr:1
    p = dpp_add<0x112, 0xf>(p);   // row_shr:2
    p = dpp_add<0x114, 0xf>(p);   // row_shr:4
    p = dpp_add<0x118, 0xf>(p);   // row_shr:8
    p = dpp_add<0x142, 0xa>(p);   // row_bcast:15 -> rows 1,3
    p = dpp_add<0x143, 0xc>(p);   // row_bcast:31 -> rows 2,3
    if (lane == 63) msum[s & 1][wv] = p;
    __syncthreads();  // the ONLY barrier per step (parity-buffered msum)

    const float4 ms = *(const float4*)(&msum[s & 1][0]);  // one ds_read_b128
    const float mu = (ms.x + ms.y) + b3mu;
    const float si = softplus_fast((ms.z + ms.w) + b3si) + 1e-5f;
    r_mean = __fadd_rn(__fadd_rn(r_mean, __fmul_rn(mu, DTF)),
                       __fmul_rn(si, meanw[s]));
    area = __fadd_rn(area, __fmul_rn(r_mean, DTF));
  }

  if (t < NMAT) {
    float mx = mats[0];
#pragma unroll
    for (int i = 1; i < NMAT; ++i) mx = fmaxf(mx, mats[i]);
    const float mm = mats[t];
    const float frac = mm / (mx + 1e-12f);
    out[b * NMAT + t] = (area * frac) / (mm + 1e-12f);
  }
}

extern "C" void kernel_launch(void* const* d_in, const int* in_sizes, int n_in,
                              void* d_out, int out_size, void* d_ws, size_t ws_size,
                              hipStream_t stream) {
  (void)in_sizes; (void)n_in; (void)ws_size; (void)out_size;
  const float* X      = (const float*)d_in[0];
  const float* r_ult  = (const float*)d_in[1];
  const float* mats   = (const float*)d_in[2];
  const float* Wp     = (const float*)d_in[3];
  const float* bp     = (const float*)d_in[4];
  const float* ln_g   = (const float*)d_in[5];
  const float* ln_b   = (const float*)d_in[6];
  const float* muW1   = (const float*)d_in[7];
  const float* mub1   = (const float*)d_in[8];
  const float* muW2   = (const float*)d_in[9];
  const float* mub2   = (const float*)d_in[10];
  const float* muW3   = (const float*)d_in[11];
  const float* mub3   = (const float*)d_in[12];
  const float* siW1   = (const float*)d_in[13];
  const float* sib1   = (const float*)d_in[14];
  const float* siW2   = (const float*)d_in[15];
  const float* sib2   = (const float*)d_in[16];
  const float* siW3   = (const float*)d_in[17];
  const float* sib3   = (const float*)d_in[18];
  float* ws = (float*)d_ws;   // 64*2520*4 = 645,120 bytes

  hipLaunchKernelGGL(vasicek_phase1_meandw,
                     dim3(NB * NSTEPS / (4 * P1UNITS)), dim3(256), 0, stream, ws);
  hipLaunchKernelGGL(vasicek_phase2_scan,
                     dim3(NB), dim3(256), 0, stream,
                     X, r_ult, mats, Wp, bp, ln_g, ln_b,
                     muW1, mub1, muW2, mub2, muW3, mub3,
                     siW1, sib1, siW2, sib2, siW3, sib3,
                     ws, (float*)d_out);
}